// Round 10
// baseline (510.037 us; speedup 1.0000x reference)
//
#include <hip/hip_runtime.h>
#include <hip/hip_bf16.h>
#include <math.h>

#define BATCH 8
#define HH 1024
#define WW 1024

__device__ __forceinline__ int reflect1024(int i) {
    i = i < 0 ? -i : i;
    return i > 1023 ? 2046 - i : i;
}

// ---------------------------------------------------------------------------
// device func: conv0 = concat(nearest(lqs,256)[3], evs[15]) -> (8,18,3,3)
// s2 p1 + bias + relu -> [B,8,128,128]. 4 px along x per thread. 32768 thr.
// ---------------------------------------------------------------------------
__device__ __forceinline__ void dev_conv0(int idx,
                                          const float* __restrict__ lqs,
                                          const float* __restrict__ evs,
                                          const float* __restrict__ w,
                                          const float* __restrict__ bias,
                                          float* __restrict__ out) {
    int q = idx & 4095;
    int b = idx >> 12;
    int qx = q & 31, oy = q >> 5;
    int iy0 = oy * 2 - 1;

    float acc[4][8];
#pragma unroll
    for (int j = 0; j < 4; ++j)
#pragma unroll
        for (int o = 0; o < 8; ++o) acc[j][o] = bias[o];

#pragma unroll
    for (int ic = 0; ic < 3; ++ic) {
        const float* ipc = lqs + (size_t)(b * 3 + ic) * HH * WW;
#pragma unroll
        for (int ky = 0; ky < 3; ++ky) {
            int iy = iy0 + ky;
            if (iy < 0) continue;
            const float* row = ipc + (size_t)iy * 4 * WW;
            float xr[9];
#pragma unroll
            for (int i = 0; i < 9; ++i) {
                int ix = 8 * qx - 1 + i;
                xr[i] = (ix >= 0) ? row[ix * 4] : 0.0f;
            }
#pragma unroll
            for (int o = 0; o < 8; ++o) {
                const float* wp = w + (o * 18 + ic) * 9 + ky * 3;
#pragma unroll
                for (int j = 0; j < 4; ++j)
#pragma unroll
                    for (int kx = 0; kx < 3; ++kx)
                        acc[j][o] = fmaf(wp[kx], xr[2 * j + kx], acc[j][o]);
            }
        }
    }
    for (int ic = 0; ic < 15; ++ic) {
        const float* ipc = evs + (size_t)(b * 15 + ic) * 65536;
#pragma unroll
        for (int ky = 0; ky < 3; ++ky) {
            int iy = iy0 + ky;
            if (iy < 0) continue;
            const float* row = ipc + iy * 256;
            const float4* r4 = (const float4*)row;
            float4 A = r4[2 * qx];
            float4 Bv = r4[2 * qx + 1];
            float m = (qx > 0) ? row[8 * qx - 1] : 0.0f;
            float xr[9] = {m, A.x, A.y, A.z, A.w, Bv.x, Bv.y, Bv.z, Bv.w};
#pragma unroll
            for (int o = 0; o < 8; ++o) {
                const float* wp = w + (o * 18 + ic + 3) * 9 + ky * 3;
#pragma unroll
                for (int j = 0; j < 4; ++j)
#pragma unroll
                    for (int kx = 0; kx < 3; ++kx)
                        acc[j][o] = fmaf(wp[kx], xr[2 * j + kx], acc[j][o]);
            }
        }
    }
#pragma unroll
    for (int o = 0; o < 8; ++o) {
        float4 v = make_float4(fmaxf(acc[0][o], 0.0f), fmaxf(acc[1][o], 0.0f),
                               fmaxf(acc[2][o], 0.0f), fmaxf(acc[3][o], 0.0f));
        *(float4*)(out + ((size_t)(b * 8 + o) << 14) + oy * 128 + qx * 4) = v;
    }
}

// ---------------------------------------------------------------------------
// device func: generic 3x3 conv, pad=1, OCT output channels per thread.
// Unsplit (R8 lesson: OCT>=8 for 1:8 load:FMA reuse); occupancy for latency
// hiding comes from co-dispatched blur blocks, not split-K.
// ---------------------------------------------------------------------------
template <int IC, int OC, int OCT, int IH, int IW, int STRIDE, bool RELU, bool HASB>
__device__ __forceinline__ void dev_convN(int idx,
                                          const float* __restrict__ in,
                                          const float* __restrict__ w,
                                          const float* __restrict__ bias,
                                          float* __restrict__ out) {
    constexpr int OH = (IH + 2 - 3) / STRIDE + 1;
    constexpr int OW = (IW + 2 - 3) / STRIDE + 1;
    constexpr int POS = OH * OW;
    constexpr int G = OC / OCT;
    if (idx >= BATCH * G * POS) return;
    int px = idx % POS;
    int g = (idx / POS) % G;
    int b = idx / (POS * G);
    int ox = px % OW, oy = px / OW;
    int iy0 = oy * STRIDE - 1, ix0 = ox * STRIDE - 1;

    float acc[OCT];
#pragma unroll
    for (int o = 0; o < OCT; ++o) acc[o] = HASB ? bias[g * OCT + o] : 0.0f;

    const float* ip = in + (size_t)b * IC * IH * IW;
    for (int ic = 0; ic < IC; ++ic) {
        const float* ipc = ip + ic * IH * IW;
        float x[9];
#pragma unroll
        for (int ky = 0; ky < 3; ++ky) {
            int iy = iy0 + ky;
#pragma unroll
            for (int kx = 0; kx < 3; ++kx) {
                int ix = ix0 + kx;
                bool ok = (iy >= 0) && (iy < IH) && (ix >= 0) && (ix < IW);
                x[ky * 3 + kx] = ok ? ipc[iy * IW + ix] : 0.0f;
            }
        }
#pragma unroll
        for (int o = 0; o < OCT; ++o) {
            const float* wp = w + ((g * OCT + o) * IC + ic) * 9;
#pragma unroll
            for (int k = 0; k < 9; ++k) acc[o] = fmaf(wp[k], x[k], acc[o]);
        }
    }
#pragma unroll
    for (int o = 0; o < OCT; ++o) {
        float v = acc[o];
        if (RELU) v = fmaxf(v, 0.0f);
        out[(size_t)(b * OC + g * OCT + o) * POS + px] = v;
    }
}

// ---------------------------------------------------------------------------
// device func: blur+guide for one 64x32 tile. Vertical-first separable 17-tap
// gaussian (sliding register windows), per-px guide MLP, z-coord quantized to
// u16 fixed point (x8192; max 7*8192=57344, err 6e-5 << tolerance).
// Independent of the lowres stream -> co-dispatched with conv stages.
// ---------------------------------------------------------------------------
__device__ __forceinline__ void dev_blur(int tile, int t,
                                         const float* __restrict__ lqs,
                                         const float* __restrict__ gw1,
                                         const float* __restrict__ gb1,
                                         const float* __restrict__ gw2,
                                         const float* __restrict__ gb2,
                                         unsigned short* __restrict__ gq) {
    __shared__ float sBH[3][32][81];
    __shared__ float sW1[48], sB1[16], sW2[16], sB2v[1];

    int bx = tile & 15;
    int by = (tile >> 4) & 31;
    int b = tile >> 9;
    int x0 = bx * 64, y0 = by * 32;

    float gv[17];
    {
        float gs = 0.0f;
#pragma unroll
        for (int i = 0; i < 17; ++i) {
            float d = (float)i - 8.0f;
            gv[i] = expf(-(d * d) * 0.125f);
            gs += gv[i];
        }
        float inv = 1.0f / gs;
#pragma unroll
        for (int i = 0; i < 17; ++i) gv[i] *= inv;
    }

    if (t < 48) sW1[t] = gw1[t];
    if (t < 16) { sB1[t] = gb1[t]; sW2[t] = gw2[t]; }
    if (t == 0) sB2v[0] = gb2[0];

    if (t < 240) {
        int c = t / 80, xo = t % 80;
        int gx = reflect1024(x0 + xo - 8);
        const float* colp = lqs + (size_t)(b * 3 + c) * HH * WW + gx;
        float win[17];
#pragma unroll
        for (int i = 0; i < 16; ++i)
            win[i] = colp[(size_t)reflect1024(y0 - 8 + i) * WW];
#pragma unroll
        for (int j = 0; j < 32; ++j) {
            win[(16 + j) % 17] = colp[(size_t)reflect1024(y0 + 8 + j) * WW];
            float acc = 0.0f;
#pragma unroll
            for (int i = 0; i < 17; ++i) acc = fmaf(gv[i], win[(j + i) % 17], acc);
            sBH[c][j][xo] = acc;
        }
    }
    __syncthreads();

    int yy = t >> 3, xs = (t & 7) * 8;
    float bcv[3][8];
#pragma unroll
    for (int c = 0; c < 3; ++c) {
        float win[17];
#pragma unroll
        for (int i = 0; i < 16; ++i) win[i] = sBH[c][yy][xs + i];
#pragma unroll
        for (int j = 0; j < 8; ++j) {
            win[(16 + j) % 17] = sBH[c][yy][xs + 16 + j];
            float acc = 0.0f;
#pragma unroll
            for (int i = 0; i < 17; ++i) acc = fmaf(gv[i], win[(j + i) % 17], acc);
            bcv[c][j] = acc;
        }
    }

    unsigned int qw[4];
#pragma unroll
    for (int j = 0; j < 8; ++j) {
        float b0 = bcv[0][j], b1 = bcv[1][j], b2 = bcv[2][j];
        float s = sB2v[0];
#pragma unroll
        for (int c = 0; c < 16; ++c) {
            float g1 = fmaf(sW1[c * 3 + 0], b0,
                       fmaf(sW1[c * 3 + 1], b1,
                       fmaf(sW1[c * 3 + 2], b2, sB1[c])));
            s = fmaf(sW2[c], fmaxf(g1, 0.0f), s);
        }
        float sig = 1.0f / (1.0f + expf(-s));
        float guide = sig * 2.0f - 0.5f;
        float fz = fminf(fmaxf(fmaf(guide, 4.0f, 3.5f), 0.0f), 7.0f);
        unsigned int q = (unsigned int)(fz * 8192.0f + 0.5f);
        if (j & 1) qw[j >> 1] |= (q << 16);
        else qw[j >> 1] = q;
    }
    size_t o = ((size_t)b << 20) + ((size_t)(y0 + yy) << 10) + x0 + xs;
    *(uint4*)(gq + o) = make_uint4(qw[0], qw[1], qw[2], qw[3]);
}

// ---------------------------------------------------------------------------
// union kernels: blocks [0,convBlocks) run the conv stage, rest run a blur
// chunk. Branch is block-uniform, so dev_blur's __syncthreads is safe.
// ---------------------------------------------------------------------------
#define GUIDE_ARGS const float* __restrict__ lqs_g, const float* __restrict__ gw1, \
    const float* __restrict__ gb1, const float* __restrict__ gw2, \
    const float* __restrict__ gb2, unsigned short* __restrict__ gq, \
    int convBlocks, int blurBase

__global__ __launch_bounds__(256) void u1_k(const float* __restrict__ lqs,
                                            const float* __restrict__ evs,
                                            const float* __restrict__ w,
                                            const float* __restrict__ bias,
                                            float* __restrict__ out, GUIDE_ARGS) {
    if ((int)blockIdx.x < convBlocks)
        dev_conv0(blockIdx.x * 256 + threadIdx.x, lqs, evs, w, bias, out);
    else
        dev_blur(blurBase + blockIdx.x - convBlocks, threadIdx.x, lqs_g, gw1, gb1, gw2, gb2, gq);
}

template <int IC, int OC, int OCT, int IH, int IW, int STRIDE, bool RELU, bool HASB>
__global__ __launch_bounds__(256) void uN_k(const float* __restrict__ in,
                                            const float* __restrict__ w,
                                            const float* __restrict__ bias,
                                            float* __restrict__ out, GUIDE_ARGS) {
    if ((int)blockIdx.x < convBlocks)
        dev_convN<IC, OC, OCT, IH, IW, STRIDE, RELU, HASB>(blockIdx.x * 256 + threadIdx.x, in, w, bias, out);
    else
        dev_blur(blurBase + blockIdx.x - convBlocks, threadIdx.x, lqs_g, gw1, gb1, gw2, gb2, gq);
}

// u5: lw1 (64 blocks) + cw0 (16 blocks) + blur
__global__ __launch_bounds__(256) void u5_k(const float* __restrict__ o3,
                                            const float* __restrict__ lw1, const float* __restrict__ lb1,
                                            float* __restrict__ xl1,
                                            const float* __restrict__ cw0, const float* __restrict__ cb0,
                                            float* __restrict__ xg0, GUIDE_ARGS) {
    int blk = blockIdx.x;
    if (blk < 64)
        dev_convN<64, 64, 8, 16, 16, 1, true, true>(blk * 256 + threadIdx.x, o3, lw1, lb1, xl1);
    else if (blk < 80)
        dev_convN<64, 64, 8, 16, 16, 2, true, true>((blk - 64) * 256 + threadIdx.x, o3, cw0, cb0, xg0);
    else
        dev_blur(blurBase + blk - 80, threadIdx.x, lqs_g, gw1, gb1, gw2, gb2, gq);
    (void)convBlocks;
}

// u6: lw2 (64 blocks, no bias/relu) + cw1 (8 blocks) + blur
__global__ __launch_bounds__(256) void u6_k(const float* __restrict__ xl1,
                                            const float* __restrict__ lw2, float* __restrict__ xl2,
                                            const float* __restrict__ xg0,
                                            const float* __restrict__ cw1, const float* __restrict__ cb1,
                                            float* __restrict__ xg1, GUIDE_ARGS) {
    int blk = blockIdx.x;
    if (blk < 64)
        dev_convN<64, 64, 8, 16, 16, 1, false, false>(blk * 256 + threadIdx.x, xl1, lw2, nullptr, xl2);
    else if (blk < 72)
        dev_convN<64, 64, 4, 8, 8, 2, true, true>((blk - 64) * 256 + threadIdx.x, xg0, cw1, cb1, xg1);
    else
        dev_blur(blurBase + blk - 72, threadIdx.x, lqs_g, gw1, gb1, gw2, gb2, gq);
    (void)convBlocks;
}

// ---------------------------------------------------------------------------
// fc1: h1[b,r] = relu(fw1[r,:] . xg1[b,:] + fb1[r]). 512 blocks, row/wave.
// ---------------------------------------------------------------------------
__global__ __launch_bounds__(256) void fc1_k(const float* __restrict__ xg1,
                                             const float* __restrict__ fw1,
                                             const float* __restrict__ fb1,
                                             float* __restrict__ h1) {
    __shared__ float xin[1024];
    int t = threadIdx.x;
    int b = blockIdx.x >> 6;
    int rgrp = blockIdx.x & 63;
    int wave = t >> 6, lane = t & 63;

    ((float4*)xin)[t] = ((const float4*)(xg1 + b * 1024))[t];
    __syncthreads();

    int r = (rgrp << 2) | wave;
    const float4* w4 = (const float4*)(fw1 + r * 1024);
    const float4* x4 = (const float4*)xin;
    float acc = 0.0f;
#pragma unroll
    for (int jj = 0; jj < 4; ++jj) {
        float4 wv = w4[lane + 64 * jj];
        float4 xv = x4[lane + 64 * jj];
        acc = fmaf(wv.x, xv.x, acc);
        acc = fmaf(wv.y, xv.y, acc);
        acc = fmaf(wv.z, xv.z, acc);
        acc = fmaf(wv.w, xv.w, acc);
    }
#pragma unroll
    for (int m = 32; m; m >>= 1) acc += __shfl_xor(acc, m, 64);
    if (lane == 0) h1[b * 256 + r] = fmaxf(acc + fb1[r], 0.0f);
}

// ---------------------------------------------------------------------------
// fc2+fc3 merged (tiny): one block per batch, h2 staged via LDS.
// ---------------------------------------------------------------------------
__global__ __launch_bounds__(256) void fc23_k(const float* __restrict__ h1,
                                              const float* __restrict__ fw2,
                                              const float* __restrict__ fb2,
                                              const float* __restrict__ fw3,
                                              const float* __restrict__ fb3,
                                              float* __restrict__ xgv) {
    __shared__ float h2[128];
    int b = blockIdx.x, t = threadIdx.x;
    int wave = t >> 6, lane = t & 63;

    float4 xv1 = ((const float4*)(h1 + b * 256))[lane];
#pragma unroll 4
    for (int i = 0; i < 32; ++i) {
        int r = wave * 32 + i;
        float4 wv = ((const float4*)(fw2 + r * 256))[lane];
        float acc = fmaf(wv.x, xv1.x, fmaf(wv.y, xv1.y, fmaf(wv.z, xv1.z, wv.w * xv1.w)));
#pragma unroll
        for (int m = 32; m; m >>= 1) acc += __shfl_xor(acc, m, 64);
        if (lane == 0) h2[r] = fmaxf(acc + fb2[r], 0.0f);
    }
    __syncthreads();

    float2 xv2 = ((const float2*)h2)[lane];
#pragma unroll 4
    for (int i = 0; i < 16; ++i) {
        int r = wave * 16 + i;
        float2 wv = ((const float2*)(fw3 + r * 128))[lane];
        float acc = fmaf(wv.x, xv2.x, wv.y * xv2.y);
#pragma unroll
        for (int m = 32; m; m >>= 1) acc += __shfl_xor(acc, m, 64);
        if (lane == 0) xgv[b * 64 + r] = acc + fb3[r];
    }
}

// ---------------------------------------------------------------------------
// fuse (R7's proven 64-block structure, now reading xl2 directly):
// bg[b,d,px] = fub[d] + sum_c fuw[d,c]*relu(xgv[b,c] + xl2[b,c,px])
// ---------------------------------------------------------------------------
__global__ __launch_bounds__(256) void fuse_k(const float* __restrict__ xgv,
                                              const float* __restrict__ xl2,
                                              const float* __restrict__ fuw,
                                              const float* __restrict__ fub,
                                              float* __restrict__ bg) {
    int px = threadIdx.x;
    int d = blockIdx.x & 7;
    int b = blockIdx.x >> 3;
    float acc = fub[d];
    for (int c = 0; c < 64; ++c) {
        float f = fmaxf(xgv[b * 64 + c] + xl2[(b * 64 + c) * 256 + px], 0.0f);
        acc = fmaf(fuw[d * 64 + c], f, acc);
    }
    bg[(b * 8 + d) * 256 + px] = acc;
}

// ---------------------------------------------------------------------------
// slice: decode u16 guide z, trilinear-sample bg (LDS-cached). 8 px/thread,
// 2048 px/block, 4096 blocks. ~50 MB traffic -> HBM-bound ~12 us.
// ---------------------------------------------------------------------------
__global__ __launch_bounds__(256) void slice_k(const unsigned short* __restrict__ gq,
                                               const float* __restrict__ bgp,
                                               float* __restrict__ out) {
    __shared__ float sBG[2048];
    int t = threadIdx.x;
    int b = blockIdx.x >> 9;
    for (int i = t; i < 2048; i += 256) sBG[i] = bgp[b * 2048 + i];
    __syncthreads();

    int off = (blockIdx.x & 511) * 2048 + t * 8;
    int Y = off >> 10, X0 = off & 1023;
    float fy = fminf(fmaxf((Y + 0.5f) * (1.0f / 64.0f) + 3.5f, 0.0f), 15.0f);
    float yf = floorf(fy);
    int yi = (int)yf;
    float ay = fy - yf;
    int yi1 = min(yi + 1, 15);

    uint4 qv = *(const uint4*)(gq + ((size_t)b << 20) + off);
    unsigned int qw[4] = {qv.x, qv.y, qv.z, qv.w};

    float val[8];
#pragma unroll
    for (int j = 0; j < 8; ++j) {
        unsigned int q = (qw[j >> 1] >> ((j & 1) * 16)) & 0xffff;
        float fz = (float)q * (1.0f / 8192.0f);
        int X = X0 + j;
        float fx = fminf(fmaxf((X + 0.5f) * (1.0f / 64.0f) + 3.5f, 0.0f), 15.0f);
        float xf = floorf(fx), zf = floorf(fz);
        int xi = (int)xf, zi = (int)zf;
        float ax = fx - xf, az = fz - zf;
        int xi1 = min(xi + 1, 15), zi1 = min(zi + 1, 7);

        const float* g0 = sBG + zi * 256;
        const float* g1p = sBG + zi1 * 256;
        int i00 = yi * 16 + xi, i01 = yi * 16 + xi1;
        int i10 = yi1 * 16 + xi, i11 = yi1 * 16 + xi1;
        float c00 = g0[i00] + az * (g1p[i00] - g0[i00]);
        float c01 = g0[i01] + az * (g1p[i01] - g0[i01]);
        float c10 = g0[i10] + az * (g1p[i10] - g0[i10]);
        float c11 = g0[i11] + az * (g1p[i11] - g0[i11]);
        float c0 = c00 + ay * (c10 - c00);
        float c1 = c01 + ay * (c11 - c01);
        val[j] = c0 + ax * (c1 - c0);
    }
    float4* op = (float4*)(out + ((size_t)b << 20) + off);
    op[0] = make_float4(val[0], val[1], val[2], val[3]);
    op[1] = make_float4(val[4], val[5], val[6], val[7]);
}

// ---------------------------------------------------------------------------
extern "C" void kernel_launch(void* const* d_in, const int* in_sizes, int n_in,
                              void* d_out, int out_size, void* d_ws, size_t ws_size,
                              hipStream_t stream) {
    const float* lqs = (const float*)d_in[0];
    const float* evs = (const float*)d_in[1];
    const float* gw1 = (const float*)d_in[2];
    const float* gb1 = (const float*)d_in[3];
    const float* gw2 = (const float*)d_in[4];
    const float* gb2 = (const float*)d_in[5];
    const float* sw0 = (const float*)d_in[6];
    const float* sb0 = (const float*)d_in[7];
    const float* sw1 = (const float*)d_in[8];
    const float* sb1 = (const float*)d_in[9];
    const float* sw2 = (const float*)d_in[10];
    const float* sb2 = (const float*)d_in[11];
    const float* sw3 = (const float*)d_in[12];
    const float* sb3 = (const float*)d_in[13];
    const float* cw0 = (const float*)d_in[14];
    const float* cb0 = (const float*)d_in[15];
    const float* cw1 = (const float*)d_in[16];
    const float* cb1 = (const float*)d_in[17];
    const float* fw1 = (const float*)d_in[18];
    const float* fb1 = (const float*)d_in[19];
    const float* fw2 = (const float*)d_in[20];
    const float* fb2 = (const float*)d_in[21];
    const float* fw3 = (const float*)d_in[22];
    const float* fb3 = (const float*)d_in[23];
    const float* lw1 = (const float*)d_in[24];
    const float* lb1 = (const float*)d_in[25];
    const float* lw2 = (const float*)d_in[26];
    const float* fuw = (const float*)d_in[27];
    const float* fub = (const float*)d_in[28];
    float* out = (float*)d_out;

    float* ws = (float*)d_ws;
    float* o0 = ws;                 // [8,8,128,128]  1048576
    float* o1 = o0 + 1048576;       // [8,16,64,64]    524288
    float* o2 = o1 + 524288;        // [8,32,32,32]    262144
    float* o3 = o2 + 262144;        // [8,64,16,16]    131072
    float* xl1 = o3 + 131072;       // [8,64,16,16]    131072
    float* xl2 = xl1 + 131072;      // [8,64,16,16]    131072
    float* xg0 = xl2 + 131072;      // [8,64,8,8]       32768
    float* xg1 = xg0 + 32768;       // [8,64,4,4]        8192
    float* h1 = xg1 + 8192;         // [8,256]           2048
    float* xgv = h1 + 2048;         // [8,64]             512
    float* bg = xgv + 512;          // [8,8,16,16]      16384
    unsigned short* gq = (unsigned short*)(bg + 16384);  // [8,1024,1024] u16 = 16.8 MB
    // total ~2.29M floats + 16.8 MB = ~26 MB

    // blur chunks: 4096 tiles over 6 union dispatches
    const int CB[6] = {683, 683, 683, 683, 683, 681};
    const int BB[6] = {0, 683, 1366, 2049, 2732, 3415};

    u1_k<<<128 + CB[0], 256, 0, stream>>>(lqs, evs, sw0, sb0, o0,
                                          lqs, gw1, gb1, gw2, gb2, gq, 128, BB[0]);
    uN_k<8, 16, 8, 128, 128, 2, true, true><<<256 + CB[1], 256, 0, stream>>>(
        o0, sw1, sb1, o1, lqs, gw1, gb1, gw2, gb2, gq, 256, BB[1]);
    uN_k<16, 32, 8, 64, 64, 2, true, true><<<128 + CB[2], 256, 0, stream>>>(
        o1, sw2, sb2, o2, lqs, gw1, gb1, gw2, gb2, gq, 128, BB[2]);
    uN_k<32, 64, 8, 32, 32, 2, true, true><<<64 + CB[3], 256, 0, stream>>>(
        o2, sw3, sb3, o3, lqs, gw1, gb1, gw2, gb2, gq, 64, BB[3]);
    u5_k<<<80 + CB[4], 256, 0, stream>>>(o3, lw1, lb1, xl1, cw0, cb0, xg0,
                                         lqs, gw1, gb1, gw2, gb2, gq, 80, BB[4]);
    u6_k<<<72 + CB[5], 256, 0, stream>>>(xl1, lw2, xl2, xg0, cw1, cb1, xg1,
                                         lqs, gw1, gb1, gw2, gb2, gq, 72, BB[5]);
    fc1_k<<<512, 256, 0, stream>>>(xg1, fw1, fb1, h1);
    fc23_k<<<BATCH, 256, 0, stream>>>(h1, fw2, fb2, fw3, fb3, xgv);
    fuse_k<<<64, 256, 0, stream>>>(xgv, xl2, fuw, fub, bg);
    slice_k<<<4096, 256, 0, stream>>>(gq, bg, out);
}

// Round 11
// 435.571 us; speedup vs baseline: 1.1710x; 1.1710x over previous
//
#include <hip/hip_runtime.h>
#include <hip/hip_bf16.h>
#include <math.h>

#define BATCH 8
#define HH 1024
#define WW 1024

__device__ __forceinline__ int reflect1024(int i) {
    i = i < 0 ? -i : i;
    return i > 1023 ? 2046 - i : i;
}

// ---------------------------------------------------------------------------
// device: conv0 = concat(nearest(lqs,256)[3], evs[15]) -> (8,18,3,3) s2 p1
// + bias + relu -> [B,8,128,128]. 4 px along x per thread. 128 blocks.
// ---------------------------------------------------------------------------
__device__ __forceinline__ void dev_conv0(int idx,
                                          const float* __restrict__ lqs,
                                          const float* __restrict__ evs,
                                          const float* __restrict__ w,
                                          const float* __restrict__ bias,
                                          float* __restrict__ out) {
    int q = idx & 4095;
    int b = idx >> 12;
    int qx = q & 31, oy = q >> 5;
    int iy0 = oy * 2 - 1;

    float acc[4][8];
#pragma unroll
    for (int j = 0; j < 4; ++j)
#pragma unroll
        for (int o = 0; o < 8; ++o) acc[j][o] = bias[o];

#pragma unroll
    for (int ic = 0; ic < 3; ++ic) {
        const float* ipc = lqs + (size_t)(b * 3 + ic) * HH * WW;
#pragma unroll
        for (int ky = 0; ky < 3; ++ky) {
            int iy = iy0 + ky;
            if (iy < 0) continue;
            const float* row = ipc + (size_t)iy * 4 * WW;
            float xr[9];
#pragma unroll
            for (int i = 0; i < 9; ++i) {
                int ix = 8 * qx - 1 + i;
                xr[i] = (ix >= 0) ? row[ix * 4] : 0.0f;
            }
#pragma unroll
            for (int o = 0; o < 8; ++o) {
                const float* wp = w + (o * 18 + ic) * 9 + ky * 3;
#pragma unroll
                for (int j = 0; j < 4; ++j)
#pragma unroll
                    for (int kx = 0; kx < 3; ++kx)
                        acc[j][o] = fmaf(wp[kx], xr[2 * j + kx], acc[j][o]);
            }
        }
    }
    for (int ic = 0; ic < 15; ++ic) {
        const float* ipc = evs + (size_t)(b * 15 + ic) * 65536;
#pragma unroll
        for (int ky = 0; ky < 3; ++ky) {
            int iy = iy0 + ky;
            if (iy < 0) continue;
            const float* row = ipc + iy * 256;
            const float4* r4 = (const float4*)row;
            float4 A = r4[2 * qx];
            float4 Bv = r4[2 * qx + 1];
            float m = (qx > 0) ? row[8 * qx - 1] : 0.0f;
            float xr[9] = {m, A.x, A.y, A.z, A.w, Bv.x, Bv.y, Bv.z, Bv.w};
#pragma unroll
            for (int o = 0; o < 8; ++o) {
                const float* wp = w + (o * 18 + ic + 3) * 9 + ky * 3;
#pragma unroll
                for (int j = 0; j < 4; ++j)
#pragma unroll
                    for (int kx = 0; kx < 3; ++kx)
                        acc[j][o] = fmaf(wp[kx], xr[2 * j + kx], acc[j][o]);
            }
        }
    }
#pragma unroll
    for (int o = 0; o < 8; ++o) {
        float4 v = make_float4(fmaxf(acc[0][o], 0.0f), fmaxf(acc[1][o], 0.0f),
                               fmaxf(acc[2][o], 0.0f), fmaxf(acc[3][o], 0.0f));
        *(float4*)(out + ((size_t)(b * 8 + o) << 14) + oy * 128 + qx * 4) = v;
    }
}

// ---------------------------------------------------------------------------
// device: unsplit 3x3 conv (OCT=8 reuse) — used only where blocks >= 256.
// ---------------------------------------------------------------------------
template <int IC, int OC, int OCT, int IH, int IW, int STRIDE, bool RELU, bool HASB>
__device__ __forceinline__ void dev_convN(int idx,
                                          const float* __restrict__ in,
                                          const float* __restrict__ w,
                                          const float* __restrict__ bias,
                                          float* __restrict__ out) {
    constexpr int OH = (IH + 2 - 3) / STRIDE + 1;
    constexpr int OW = (IW + 2 - 3) / STRIDE + 1;
    constexpr int POS = OH * OW;
    constexpr int G = OC / OCT;
    if (idx >= BATCH * G * POS) return;
    int px = idx % POS;
    int g = (idx / POS) % G;
    int b = idx / (POS * G);
    int ox = px % OW, oy = px / OW;
    int iy0 = oy * STRIDE - 1, ix0 = ox * STRIDE - 1;

    float acc[OCT];
#pragma unroll
    for (int o = 0; o < OCT; ++o) acc[o] = HASB ? bias[g * OCT + o] : 0.0f;

    const float* ip = in + (size_t)b * IC * IH * IW;
    for (int ic = 0; ic < IC; ++ic) {
        const float* ipc = ip + ic * IH * IW;
        float x[9];
#pragma unroll
        for (int ky = 0; ky < 3; ++ky) {
            int iy = iy0 + ky;
#pragma unroll
            for (int kx = 0; kx < 3; ++kx) {
                int ix = ix0 + kx;
                bool ok = (iy >= 0) && (iy < IH) && (ix >= 0) && (ix < IW);
                x[ky * 3 + kx] = ok ? ipc[iy * IW + ix] : 0.0f;
            }
        }
#pragma unroll
        for (int o = 0; o < OCT; ++o) {
            const float* wp = w + ((g * OCT + o) * IC + ic) * 9;
#pragma unroll
            for (int k = 0; k < 9; ++k) acc[o] = fmaf(wp[k], x[k], acc[o]);
        }
    }
#pragma unroll
    for (int o = 0; o < OCT; ++o) {
        float v = acc[o];
        if (RELU) v = fmaxf(v, 0.0f);
        out[(size_t)(b * OC + g * OCT + o) * POS + px] = v;
    }
}

// ---------------------------------------------------------------------------
// device: split-K 3x3 conv partials (R7-verified shapes: OCT=8, 512 blocks).
// ---------------------------------------------------------------------------
template <int IC, int OC, int OCT, int IH, int IW, int STRIDE, int SPLIT>
__device__ __forceinline__ void dev_convS(int idx,
                                          const float* __restrict__ in,
                                          const float* __restrict__ w,
                                          float* __restrict__ part) {
    constexpr int OH = (IH + 2 - 3) / STRIDE + 1;
    constexpr int OW = (IW + 2 - 3) / STRIDE + 1;
    constexpr int POS = OH * OW;
    constexpr int G = OC / OCT;
    constexpr int TOT = BATCH * G * POS;
    constexpr int ICS = IC / SPLIT;
    constexpr int N = BATCH * OC * POS;
    if (idx >= TOT * SPLIT) return;
    int s = idx / TOT, r = idx % TOT;
    int px = r % POS;
    int g = (r / POS) % G;
    int b = r / (POS * G);
    int ox = px % OW, oy = px / OW;
    int iy0 = oy * STRIDE - 1, ix0 = ox * STRIDE - 1;

    float acc[OCT];
#pragma unroll
    for (int o = 0; o < OCT; ++o) acc[o] = 0.0f;

    const float* ip = in + (size_t)b * IC * IH * IW;
    for (int ic = s * ICS; ic < (s + 1) * ICS; ++ic) {
        const float* ipc = ip + ic * IH * IW;
        float x[9];
#pragma unroll
        for (int ky = 0; ky < 3; ++ky) {
            int iy = iy0 + ky;
#pragma unroll
            for (int kx = 0; kx < 3; ++kx) {
                int ix = ix0 + kx;
                bool ok = (iy >= 0) && (iy < IH) && (ix >= 0) && (ix < IW);
                x[ky * 3 + kx] = ok ? ipc[iy * IW + ix] : 0.0f;
            }
        }
#pragma unroll
        for (int o = 0; o < OCT; ++o) {
            const float* wp = w + ((g * OCT + o) * IC + ic) * 9;
#pragma unroll
            for (int k = 0; k < 9; ++k) acc[o] = fmaf(wp[k], x[k], acc[o]);
        }
    }
#pragma unroll
    for (int o = 0; o < OCT; ++o)
        part[(size_t)s * N + (size_t)(b * OC + g * OCT + o) * POS + px] = acc[o];
}

// ---------------------------------------------------------------------------
// device: reduce split-K partials + bias + relu
// ---------------------------------------------------------------------------
template <int OC, int POS, int SPLIT, bool RELU, bool HASB>
__device__ __forceinline__ void dev_reduce(int idx,
                                           const float* __restrict__ part,
                                           const float* __restrict__ bias,
                                           float* __restrict__ out) {
    constexpr int N = BATCH * OC * POS;
    if (idx >= N) return;
    int oc = (idx / POS) % OC;
    float a = HASB ? bias[oc] : 0.0f;
#pragma unroll
    for (int s = 0; s < SPLIT; ++s) a += part[(size_t)s * N + idx];
    out[idx] = RELU ? fmaxf(a, 0.0f) : a;
}

// ---------------------------------------------------------------------------
// device: blur+guide for one 64x32 tile (R10-verified). Writes guide z as u16
// fixed-point (x8192, err 6e-5 << tol). Independent of lowres stream.
// ---------------------------------------------------------------------------
__device__ __forceinline__ void dev_blur(int tile, int t,
                                         const float* __restrict__ lqs,
                                         const float* __restrict__ gw1,
                                         const float* __restrict__ gb1,
                                         const float* __restrict__ gw2,
                                         const float* __restrict__ gb2,
                                         unsigned short* __restrict__ gq) {
    __shared__ float sBH[3][32][81];
    __shared__ float sW1[48], sB1[16], sW2[16], sB2v[1];

    int bx = tile & 15;
    int by = (tile >> 4) & 31;
    int b = tile >> 9;
    int x0 = bx * 64, y0 = by * 32;

    float gv[17];
    {
        float gs = 0.0f;
#pragma unroll
        for (int i = 0; i < 17; ++i) {
            float d = (float)i - 8.0f;
            gv[i] = expf(-(d * d) * 0.125f);
            gs += gv[i];
        }
        float inv = 1.0f / gs;
#pragma unroll
        for (int i = 0; i < 17; ++i) gv[i] *= inv;
    }

    if (t < 48) sW1[t] = gw1[t];
    if (t < 16) { sB1[t] = gb1[t]; sW2[t] = gw2[t]; }
    if (t == 0) sB2v[0] = gb2[0];

    if (t < 240) {
        int c = t / 80, xo = t % 80;
        int gx = reflect1024(x0 + xo - 8);
        const float* colp = lqs + (size_t)(b * 3 + c) * HH * WW + gx;
        float win[17];
#pragma unroll
        for (int i = 0; i < 16; ++i)
            win[i] = colp[(size_t)reflect1024(y0 - 8 + i) * WW];
#pragma unroll
        for (int j = 0; j < 32; ++j) {
            win[(16 + j) % 17] = colp[(size_t)reflect1024(y0 + 8 + j) * WW];
            float acc = 0.0f;
#pragma unroll
            for (int i = 0; i < 17; ++i) acc = fmaf(gv[i], win[(j + i) % 17], acc);
            sBH[c][j][xo] = acc;
        }
    }
    __syncthreads();

    int yy = t >> 3, xs = (t & 7) * 8;
    float bcv[3][8];
#pragma unroll
    for (int c = 0; c < 3; ++c) {
        float win[17];
#pragma unroll
        for (int i = 0; i < 16; ++i) win[i] = sBH[c][yy][xs + i];
#pragma unroll
        for (int j = 0; j < 8; ++j) {
            win[(16 + j) % 17] = sBH[c][yy][xs + 16 + j];
            float acc = 0.0f;
#pragma unroll
            for (int i = 0; i < 17; ++i) acc = fmaf(gv[i], win[(j + i) % 17], acc);
            bcv[c][j] = acc;
        }
    }

    unsigned int qw[4];
#pragma unroll
    for (int j = 0; j < 8; ++j) {
        float b0 = bcv[0][j], b1 = bcv[1][j], b2 = bcv[2][j];
        float s = sB2v[0];
#pragma unroll
        for (int c = 0; c < 16; ++c) {
            float g1 = fmaf(sW1[c * 3 + 0], b0,
                       fmaf(sW1[c * 3 + 1], b1,
                       fmaf(sW1[c * 3 + 2], b2, sB1[c])));
            s = fmaf(sW2[c], fmaxf(g1, 0.0f), s);
        }
        float sig = 1.0f / (1.0f + expf(-s));
        float guide = sig * 2.0f - 0.5f;
        float fz = fminf(fmaxf(fmaf(guide, 4.0f, 3.5f), 0.0f), 7.0f);
        unsigned int q = (unsigned int)(fz * 8192.0f + 0.5f);
        if (j & 1) qw[j >> 1] |= (q << 16);
        else qw[j >> 1] = q;
    }
    size_t o = ((size_t)b << 20) + ((size_t)(y0 + yy) << 10) + x0 + xs;
    *(uint4*)(gq + o) = make_uint4(qw[0], qw[1], qw[2], qw[3]);
}

// ---------------------------------------------------------------------------
// union kernels: blocks [0,convBlocks) run the lowres stage (split-K, high
// parallelism — R10 lesson: conv side must be many short blocks), rest run
// blur tiles. Branch is block-uniform -> dev_blur's __syncthreads is safe.
// ---------------------------------------------------------------------------
#define GUIDE_ARGS const float* __restrict__ lqs_g, const float* __restrict__ gw1, \
    const float* __restrict__ gb1, const float* __restrict__ gw2, \
    const float* __restrict__ gb2, unsigned short* __restrict__ gq, \
    int convBlocks, int blurBase
#define GUIDE_PASS lqs_g, gw1, gb1, gw2, gb2, gq

__global__ __launch_bounds__(256) void u1_k(const float* __restrict__ lqs,
                                            const float* __restrict__ evs,
                                            const float* __restrict__ w,
                                            const float* __restrict__ bias,
                                            float* __restrict__ out, GUIDE_ARGS) {
    if ((int)blockIdx.x < convBlocks)
        dev_conv0(blockIdx.x * 256 + threadIdx.x, lqs, evs, w, bias, out);
    else
        dev_blur(blurBase + blockIdx.x - convBlocks, threadIdx.x, GUIDE_PASS);
}

template <int IC, int OC, int OCT, int IH, int IW, int STRIDE, bool RELU, bool HASB>
__global__ __launch_bounds__(256) void uN_k(const float* __restrict__ in,
                                            const float* __restrict__ w,
                                            const float* __restrict__ bias,
                                            float* __restrict__ out, GUIDE_ARGS) {
    if ((int)blockIdx.x < convBlocks)
        dev_convN<IC, OC, OCT, IH, IW, STRIDE, RELU, HASB>(blockIdx.x * 256 + threadIdx.x, in, w, bias, out);
    else
        dev_blur(blurBase + blockIdx.x - convBlocks, threadIdx.x, GUIDE_PASS);
}

template <int IC, int OC, int OCT, int IH, int IW, int STRIDE, int SPLIT>
__global__ __launch_bounds__(256) void uS_k(const float* __restrict__ in,
                                            const float* __restrict__ w,
                                            float* __restrict__ part, GUIDE_ARGS) {
    if ((int)blockIdx.x < convBlocks)
        dev_convS<IC, OC, OCT, IH, IW, STRIDE, SPLIT>(blockIdx.x * 256 + threadIdx.x, in, w, part);
    else
        dev_blur(blurBase + blockIdx.x - convBlocks, threadIdx.x, GUIDE_PASS);
}

template <int OC, int POS, int SPLIT, bool RELU, bool HASB>
__global__ __launch_bounds__(256) void uR_k(const float* __restrict__ part,
                                            const float* __restrict__ bias,
                                            float* __restrict__ out, GUIDE_ARGS) {
    if ((int)blockIdx.x < convBlocks)
        dev_reduce<OC, POS, SPLIT, RELU, HASB>(blockIdx.x * 256 + threadIdx.x, part, bias, out);
    else
        dev_blur(blurBase + blockIdx.x - convBlocks, threadIdx.x, GUIDE_PASS);
}

// u7: lw1 split-8 (512 blocks) || cw0 split-16 (256 blocks) — both read o3
__global__ __launch_bounds__(256) void u7_k(const float* __restrict__ o3,
                                            const float* __restrict__ lw1, float* __restrict__ partA,
                                            const float* __restrict__ cw0, float* __restrict__ partB) {
    int blk = blockIdx.x;
    if (blk < 512)
        dev_convS<64, 64, 8, 16, 16, 1, 8>(blk * 256 + threadIdx.x, o3, lw1, partA);
    else
        dev_convS<64, 64, 8, 16, 16, 2, 16>((blk - 512) * 256 + threadIdx.x, o3, cw0, partB);
}

// u8: red_lw1 (512 blocks) || red_cw0 (128 blocks)
__global__ __launch_bounds__(256) void u8_k(const float* __restrict__ partA,
                                            const float* __restrict__ lb1, float* __restrict__ xl1,
                                            const float* __restrict__ partB,
                                            const float* __restrict__ cb0, float* __restrict__ xg0) {
    int blk = blockIdx.x;
    if (blk < 512)
        dev_reduce<64, 256, 8, true, true>(blk * 256 + threadIdx.x, partA, lb1, xl1);
    else
        dev_reduce<64, 64, 16, true, true>((blk - 512) * 256 + threadIdx.x, partB, cb0, xg0);
}

// u9: lw2 split-8 (512 blocks) || cw1 split-16 (128 blocks)
__global__ __launch_bounds__(256) void u9_k(const float* __restrict__ xl1,
                                            const float* __restrict__ lw2, float* __restrict__ partC,
                                            const float* __restrict__ xg0,
                                            const float* __restrict__ cw1, float* __restrict__ partD) {
    int blk = blockIdx.x;
    if (blk < 512)
        dev_convS<64, 64, 8, 16, 16, 1, 8>(blk * 256 + threadIdx.x, xl1, lw2, partC);
    else
        dev_convS<64, 64, 4, 8, 8, 2, 16>((blk - 512) * 256 + threadIdx.x, xg0, cw1, partD);
}

// ---------------------------------------------------------------------------
// fc1 (R7-verified): folds cw1's split-16 reduce (+cb1+relu) into xin, then
// h1[b,r] = relu(fw1[r,:] . xin + fb1[r]). 512 blocks, 1 row per wave.
// ---------------------------------------------------------------------------
__global__ __launch_bounds__(256) void fc1_k(const float* __restrict__ part_cw1,
                                             const float* __restrict__ cb1,
                                             const float* __restrict__ fw1,
                                             const float* __restrict__ fb1,
                                             float* __restrict__ h1) {
    __shared__ float xin[1024];
    int t = threadIdx.x;
    int b = blockIdx.x >> 6;
    int rgrp = blockIdx.x & 63;
    int wave = t >> 6, lane = t & 63;

    for (int i = t; i < 1024; i += 256) {
        float v = cb1[i >> 4];
#pragma unroll
        for (int s = 0; s < 16; ++s) v += part_cw1[s * 8192 + b * 1024 + i];
        xin[i] = fmaxf(v, 0.0f);
    }
    __syncthreads();

    int r = (rgrp << 2) | wave;
    const float4* w4 = (const float4*)(fw1 + r * 1024);
    const float4* x4 = (const float4*)xin;
    float acc = 0.0f;
#pragma unroll
    for (int jj = 0; jj < 4; ++jj) {
        float4 wv = w4[lane + 64 * jj];
        float4 xv = x4[lane + 64 * jj];
        acc = fmaf(wv.x, xv.x, acc);
        acc = fmaf(wv.y, xv.y, acc);
        acc = fmaf(wv.z, xv.z, acc);
        acc = fmaf(wv.w, xv.w, acc);
    }
#pragma unroll
    for (int m = 32; m; m >>= 1) acc += __shfl_xor(acc, m, 64);
    if (lane == 0) h1[b * 256 + r] = fmaxf(acc + fb1[r], 0.0f);
}

// ---------------------------------------------------------------------------
// fc2+fc3 (tiny, reads only h1/weights): one block per batch.
// ---------------------------------------------------------------------------
__global__ __launch_bounds__(256) void fc23_k(const float* __restrict__ h1,
                                              const float* __restrict__ fw2,
                                              const float* __restrict__ fb2,
                                              const float* __restrict__ fw3,
                                              const float* __restrict__ fb3,
                                              float* __restrict__ xgv) {
    __shared__ float h2[128];
    int b = blockIdx.x, t = threadIdx.x;
    int wave = t >> 6, lane = t & 63;

    float4 xv1 = ((const float4*)(h1 + b * 256))[lane];
#pragma unroll 4
    for (int i = 0; i < 32; ++i) {
        int r = wave * 32 + i;
        float4 wv = ((const float4*)(fw2 + r * 256))[lane];
        float acc = fmaf(wv.x, xv1.x, fmaf(wv.y, xv1.y, fmaf(wv.z, xv1.z, wv.w * xv1.w)));
#pragma unroll
        for (int m = 32; m; m >>= 1) acc += __shfl_xor(acc, m, 64);
        if (lane == 0) h2[r] = fmaxf(acc + fb2[r], 0.0f);
    }
    __syncthreads();

    float2 xv2 = ((const float2*)h2)[lane];
#pragma unroll 4
    for (int i = 0; i < 16; ++i) {
        int r = wave * 16 + i;
        float2 wv = ((const float2*)(fw3 + r * 128))[lane];
        float acc = fmaf(wv.x, xv2.x, wv.y * xv2.y);
#pragma unroll
        for (int m = 32; m; m >>= 1) acc += __shfl_xor(acc, m, 64);
        if (lane == 0) xgv[b * 64 + r] = acc + fb3[r];
    }
}

// ---------------------------------------------------------------------------
// fuse (R7-verified 64-block structure, folds lw2's split-8 partials):
// bg[b,d,px] = fub[d] + sum_c fuw[d,c]*relu(xgv[b,c] + sum_s partC[s,...])
// ---------------------------------------------------------------------------
__global__ __launch_bounds__(256) void fuse_k(const float* __restrict__ xgv,
                                              const float* __restrict__ part_lw2,
                                              const float* __restrict__ fuw,
                                              const float* __restrict__ fub,
                                              float* __restrict__ bg) {
    int px = threadIdx.x;
    int d = blockIdx.x & 7;
    int b = blockIdx.x >> 3;
    float acc = fub[d];
    for (int c = 0; c < 64; ++c) {
        int base = (b * 64 + c) * 256 + px;
        float xlv = 0.0f;
#pragma unroll
        for (int s = 0; s < 8; ++s) xlv += part_lw2[s * 131072 + base];
        float f = fmaxf(xgv[b * 64 + c] + xlv, 0.0f);
        acc = fmaf(fuw[d * 64 + c], f, acc);
    }
    bg[(b * 8 + d) * 256 + px] = acc;
}

// ---------------------------------------------------------------------------
// slice (R10-verified): decode u16 guide z, trilinear-sample LDS-cached bg.
// ---------------------------------------------------------------------------
__global__ __launch_bounds__(256) void slice_k(const unsigned short* __restrict__ gq,
                                               const float* __restrict__ bgp,
                                               float* __restrict__ out) {
    __shared__ float sBG[2048];
    int t = threadIdx.x;
    int b = blockIdx.x >> 9;
    for (int i = t; i < 2048; i += 256) sBG[i] = bgp[b * 2048 + i];
    __syncthreads();

    int off = (blockIdx.x & 511) * 2048 + t * 8;
    int Y = off >> 10, X0 = off & 1023;
    float fy = fminf(fmaxf((Y + 0.5f) * (1.0f / 64.0f) + 3.5f, 0.0f), 15.0f);
    float yf = floorf(fy);
    int yi = (int)yf;
    float ay = fy - yf;
    int yi1 = min(yi + 1, 15);

    uint4 qv = *(const uint4*)(gq + ((size_t)b << 20) + off);
    unsigned int qw[4] = {qv.x, qv.y, qv.z, qv.w};

    float val[8];
#pragma unroll
    for (int j = 0; j < 8; ++j) {
        unsigned int q = (qw[j >> 1] >> ((j & 1) * 16)) & 0xffff;
        float fz = (float)q * (1.0f / 8192.0f);
        int X = X0 + j;
        float fx = fminf(fmaxf((X + 0.5f) * (1.0f / 64.0f) + 3.5f, 0.0f), 15.0f);
        float xf = floorf(fx), zf = floorf(fz);
        int xi = (int)xf, zi = (int)zf;
        float ax = fx - xf, az = fz - zf;
        int xi1 = min(xi + 1, 15), zi1 = min(zi + 1, 7);

        const float* g0 = sBG + zi * 256;
        const float* g1p = sBG + zi1 * 256;
        int i00 = yi * 16 + xi, i01 = yi * 16 + xi1;
        int i10 = yi1 * 16 + xi, i11 = yi1 * 16 + xi1;
        float c00 = g0[i00] + az * (g1p[i00] - g0[i00]);
        float c01 = g0[i01] + az * (g1p[i01] - g0[i01]);
        float c10 = g0[i10] + az * (g1p[i10] - g0[i10]);
        float c11 = g0[i11] + az * (g1p[i11] - g0[i11]);
        float c0 = c00 + ay * (c10 - c00);
        float c1 = c01 + ay * (c11 - c01);
        val[j] = c0 + ax * (c1 - c0);
    }
    float4* op = (float4*)(out + ((size_t)b << 20) + off);
    op[0] = make_float4(val[0], val[1], val[2], val[3]);
    op[1] = make_float4(val[4], val[5], val[6], val[7]);
}

// ---------------------------------------------------------------------------
extern "C" void kernel_launch(void* const* d_in, const int* in_sizes, int n_in,
                              void* d_out, int out_size, void* d_ws, size_t ws_size,
                              hipStream_t stream) {
    const float* lqs = (const float*)d_in[0];
    const float* evs = (const float*)d_in[1];
    const float* gw1 = (const float*)d_in[2];
    const float* gb1 = (const float*)d_in[3];
    const float* gw2 = (const float*)d_in[4];
    const float* gb2 = (const float*)d_in[5];
    const float* sw0 = (const float*)d_in[6];
    const float* sb0 = (const float*)d_in[7];
    const float* sw1 = (const float*)d_in[8];
    const float* sb1 = (const float*)d_in[9];
    const float* sw2 = (const float*)d_in[10];
    const float* sb2 = (const float*)d_in[11];
    const float* sw3 = (const float*)d_in[12];
    const float* sb3 = (const float*)d_in[13];
    const float* cw0 = (const float*)d_in[14];
    const float* cb0 = (const float*)d_in[15];
    const float* cw1 = (const float*)d_in[16];
    const float* cb1 = (const float*)d_in[17];
    const float* fw1 = (const float*)d_in[18];
    const float* fb1 = (const float*)d_in[19];
    const float* fw2 = (const float*)d_in[20];
    const float* fb2 = (const float*)d_in[21];
    const float* fw3 = (const float*)d_in[22];
    const float* fb3 = (const float*)d_in[23];
    const float* lw1 = (const float*)d_in[24];
    const float* lb1 = (const float*)d_in[25];
    const float* lw2 = (const float*)d_in[26];
    const float* fuw = (const float*)d_in[27];
    const float* fub = (const float*)d_in[28];
    float* out = (float*)d_out;

    float* ws = (float*)d_ws;
    float* o0 = ws;                      // 1048576
    float* o1 = o0 + 1048576;            //  524288
    float* o2 = o1 + 524288;             //  262144
    float* o3 = o2 + 262144;             //  131072
    float* xl1 = o3 + 131072;            //  131072
    float* xg0 = xl1 + 131072;           //   32768
    float* h1 = xg0 + 32768;             //    2048
    float* xgv = h1 + 2048;              //     512
    float* bg = xgv + 512;               //   16384
    float* partA = bg + 16384;           // 1048576 (conv2/conv3/lw1, sequential reuse)
    float* partB = partA + 1048576;      //  524288 (cw0)
    float* partC = partB + 524288;       // 1048576 (lw2, persists to fuse)
    float* partD = partC + 1048576;      //  131072 (cw1, persists to fc1)
    unsigned short* gq = (unsigned short*)(partD + 131072);  // 8M u16 = 16.8 MB
    // total ~4.9M floats (19.6 MB) + 16.8 MB = ~36.4 MB

    // blur: 4096 tiles over u1..u6
    const int BC[6] = {700, 700, 700, 700, 700, 596};
    const int BB[6] = {0, 700, 1400, 2100, 2800, 3500};

    u1_k<<<128 + BC[0], 256, 0, stream>>>(lqs, evs, sw0, sb0, o0,
                                          lqs, gw1, gb1, gw2, gb2, gq, 128, BB[0]);
    uN_k<8, 16, 8, 128, 128, 2, true, true><<<256 + BC[1], 256, 0, stream>>>(
        o0, sw1, sb1, o1, lqs, gw1, gb1, gw2, gb2, gq, 256, BB[1]);
    uS_k<16, 32, 8, 64, 64, 2, 4><<<512 + BC[2], 256, 0, stream>>>(
        o1, sw2, partA, lqs, gw1, gb1, gw2, gb2, gq, 512, BB[2]);
    uR_k<32, 1024, 4, true, true><<<1024 + BC[3], 256, 0, stream>>>(
        partA, sb2, o2, lqs, gw1, gb1, gw2, gb2, gq, 1024, BB[3]);
    uS_k<32, 64, 8, 32, 32, 2, 8><<<512 + BC[4], 256, 0, stream>>>(
        o2, sw3, partA, lqs, gw1, gb1, gw2, gb2, gq, 512, BB[4]);
    uR_k<64, 256, 8, true, true><<<512 + BC[5], 256, 0, stream>>>(
        partA, sb3, o3, lqs, gw1, gb1, gw2, gb2, gq, 512, BB[5]);
    // parallel pairs on o3 and successors
    u7_k<<<768, 256, 0, stream>>>(o3, lw1, partA, cw0, partB);
    u8_k<<<640, 256, 0, stream>>>(partA, lb1, xl1, partB, cb0, xg0);
    u9_k<<<640, 256, 0, stream>>>(xl1, lw2, partC, xg0, cw1, partD);
    fc1_k<<<512, 256, 0, stream>>>(partD, cb1, fw1, fb1, h1);
    fc23_k<<<BATCH, 256, 0, stream>>>(h1, fw2, fb2, fw3, fb3, xgv);
    fuse_k<<<64, 256, 0, stream>>>(xgv, partC, fuw, fub, bg);
    slice_k<<<4096, 256, 0, stream>>>(gq, bg, out);
}